// Round 2
// baseline (298.320 us; speedup 1.0000x reference)
//
#include <hip/hip_runtime.h>

#define N_CLS 28
#define DIM   64

// deg[v] = number of edges with dst == v (self-loop +1 added later)
__global__ void k_deg(const int* __restrict__ dst, int* __restrict__ deg, int E) {
    int e = blockIdx.x * blockDim.x + threadIdx.x;
    if (e < E) atomicAdd(&deg[dst[e]], 1);
}

// T1 = emb_table @ W1   [28,64]
__global__ void k_t1(const float* __restrict__ emb, const float* __restrict__ W1,
                     float* __restrict__ T1) {
    int idx = blockIdx.x * blockDim.x + threadIdx.x;
    if (idx >= N_CLS * DIM) return;
    int r = idx >> 6, j = idx & 63;
    float acc = 0.f;
#pragma unroll
    for (int k = 0; k < DIM; ++k) acc += emb[r * DIM + k] * W1[k * DIM + j];
    T1[idx] = acc;
}

// u = W2 @ lin_W  [64];  c = b2·lin_W + lin_b  (scalar)
__global__ void k_uc(const float* __restrict__ W2, const float* __restrict__ linW,
                     const float* __restrict__ b2, const float* __restrict__ linb,
                     float* __restrict__ u, float* __restrict__ cc) {
    int k = threadIdx.x; // 64 threads, one wave
    float acc = 0.f;
#pragma unroll
    for (int j = 0; j < DIM; ++j) acc += W2[k * DIM + j] * linW[j];
    u[k] = acc;
    float p = b2[k] * linW[k];
#pragma unroll
    for (int off = 32; off; off >>= 1) p += __shfl_down(p, off);
    if (k == 0) cc[0] = p + linb[0];
}

// dinv[v] = rsqrt(deg+1); seed cnt with self-loop contribution dinv[v] at class x[v]
__global__ void k_prep(const int* __restrict__ deg, const int* __restrict__ x,
                       float* __restrict__ dinv, float* __restrict__ cnt, int N) {
    int v = blockIdx.x * blockDim.x + threadIdx.x;
    if (v >= N) return;
    float dv = rsqrtf((float)(deg[v] + 1));
    dinv[v] = dv;
    cnt[v * N_CLS + x[v]] = dv; // cnt pre-zeroed by memset
}

// cnt[dst][x[src]] += dinv[src]   (layer-1 message pass collapsed to 28-bin hist)
__global__ void k_edge1(const int* __restrict__ src, const int* __restrict__ dst,
                        const int* __restrict__ x, const float* __restrict__ dinv,
                        float* __restrict__ cnt, int E) {
    int e = blockIdx.x * blockDim.x + threadIdx.x;
    if (e >= E) return;
    int s = src[e], d = dst[e];
    atomicAdd(&cnt[(size_t)d * N_CLS + x[s]], dinv[s]);
}

// per node: h1[j] = relu(dinv[v] * sum_c cnt[v][c]*T1[c][j] + b1[j]);  s[v] = sum_j h1[j]*u[j]
__global__ void k_node1(const float* __restrict__ cnt, const float* __restrict__ T1,
                        const float* __restrict__ dinv, const float* __restrict__ b1,
                        const float* __restrict__ u, float* __restrict__ s_out, int N) {
    __shared__ float T1s[N_CLS * DIM];
    int tid = threadIdx.x;
    for (int i = tid; i < N_CLS * DIM; i += blockDim.x) T1s[i] = T1[i];
    __syncthreads();
    int wave = tid >> 6, lane = tid & 63;
    int v = blockIdx.x * (blockDim.x >> 6) + wave;
    if (v >= N) return;
    // coalesced load of the 28 cnt values across lanes, broadcast via shfl
    float cl = (lane < N_CLS) ? cnt[(size_t)v * N_CLS + lane] : 0.f;
    float acc = 0.f;
#pragma unroll
    for (int c = 0; c < N_CLS; ++c) acc += __shfl(cl, c) * T1s[c * DIM + lane];
    float h = fmaxf(dinv[v] * acc + b1[lane], 0.f);
    float p = h * u[lane];
#pragma unroll
    for (int off = 32; off; off >>= 1) p += __shfl_down(p, off);
    if (lane == 0) s_out[v] = p;
}

// acc2[dst] += dinv[src]*dinv[dst]*s[src]   (layer-2 pass is scalar)
__global__ void k_edge2(const int* __restrict__ src, const int* __restrict__ dst,
                        const float* __restrict__ dinv, const float* __restrict__ s,
                        float* __restrict__ acc2, int E) {
    int e = blockIdx.x * blockDim.x + threadIdx.x;
    if (e >= E) return;
    int a = src[e], b = dst[e];
    atomicAdd(&acc2[b], dinv[a] * dinv[b] * s[a]);
}

// y[v] = acc2[v] + dinv[v]^2 * s[v] + c;  out[batch[v]] += y[v]
__global__ void k_final(const float* __restrict__ acc2, const float* __restrict__ dinv,
                        const float* __restrict__ s, const float* __restrict__ cc,
                        const int* __restrict__ batch, float* __restrict__ out, int N) {
    int v = blockIdx.x * blockDim.x + threadIdx.x;
    if (v >= N) return;
    float dv = dinv[v];
    float y = acc2[v] + dv * dv * s[v] + cc[0];
    atomicAdd(&out[batch[v]], y);
}

extern "C" void kernel_launch(void* const* d_in, const int* in_sizes, int n_in,
                              void* d_out, int out_size, void* d_ws, size_t ws_size,
                              hipStream_t stream) {
    const int*   x     = (const int*)d_in[0];
    const int*   ei    = (const int*)d_in[1];
    const int*   batch = (const int*)d_in[3];
    const float* emb   = (const float*)d_in[4];
    const float* W1    = (const float*)d_in[5];
    const float* b1    = (const float*)d_in[6];
    const float* W2    = (const float*)d_in[7];
    const float* b2    = (const float*)d_in[8];
    const float* linW  = (const float*)d_in[9];
    const float* linb  = (const float*)d_in[10];

    const int N = in_sizes[0];
    const int E = in_sizes[1] / 2;
    const int* srcp = ei;
    const int* dstp = ei + E;
    float* out = (float*)d_out;

    char* w = (char*)d_ws;
    int*   deg  = (int*)w;    w += (size_t)N * 4;
    float* dinv = (float*)w;  w += (size_t)N * 4;
    float* cnt  = (float*)w;  w += (size_t)N * N_CLS * 4;
    float* T1   = (float*)w;  w += (size_t)N_CLS * DIM * 4;
    float* u    = (float*)w;  w += DIM * 4;
    float* cc   = (float*)w;  w += 16;
    float* s    = (float*)w;  w += (size_t)N * 4;
    float* acc2 = (float*)w;  w += (size_t)N * 4;

    hipMemsetAsync(deg,  0, (size_t)N * 4, stream);
    hipMemsetAsync(cnt,  0, (size_t)N * N_CLS * 4, stream);
    hipMemsetAsync(acc2, 0, (size_t)N * 4, stream);
    hipMemsetAsync(out,  0, (size_t)out_size * 4, stream);

    k_deg<<<(E + 255) / 256, 256, 0, stream>>>(dstp, deg, E);
    k_t1<<<(N_CLS * DIM + 255) / 256, 256, 0, stream>>>(emb, W1, T1);
    k_uc<<<1, 64, 0, stream>>>(W2, linW, b2, linb, u, cc);
    k_prep<<<(N + 255) / 256, 256, 0, stream>>>(deg, x, dinv, cnt, N);
    k_edge1<<<(E + 255) / 256, 256, 0, stream>>>(srcp, dstp, x, dinv, cnt, E);
    k_node1<<<(N + 3) / 4, 256, 0, stream>>>(cnt, T1, dinv, b1, u, s, N);
    k_edge2<<<(E + 255) / 256, 256, 0, stream>>>(srcp, dstp, dinv, s, acc2, E);
    k_final<<<(N + 255) / 256, 256, 0, stream>>>(acc2, dinv, s, cc, batch, out, N);
}

// Round 3
// 291.714 us; speedup vs baseline: 1.0226x; 1.0226x over previous
//
#include <hip/hip_runtime.h>

#define N_CLS 28
#define DIM   64

// deg[v] = number of in-edges (self-loop handled analytically later)
__global__ void k_deg(const int* __restrict__ dst, int* __restrict__ deg, int E) {
    int e = blockIdx.x * blockDim.x + threadIdx.x;
    if (e < E) atomicAdd(&deg[dst[e]], 1);
}

// Fused constants: blocks 0..27 compute T1 = emb@W1 row r; block 28 computes
// u = W2@lin_W and cc = b2·lin_W + lin_b.
__global__ void k_const(const float* __restrict__ emb, const float* __restrict__ W1,
                        const float* __restrict__ W2, const float* __restrict__ linW,
                        const float* __restrict__ b2, const float* __restrict__ linb,
                        float* __restrict__ T1, float* __restrict__ u, float* __restrict__ cc) {
    int j = threadIdx.x;   // 64 threads
    int r = blockIdx.x;
    if (r < N_CLS) {
        float acc = 0.f;
#pragma unroll
        for (int k = 0; k < DIM; ++k) acc += emb[r * DIM + k] * W1[k * DIM + j];
        T1[r * DIM + j] = acc;
    } else {
        float acc = 0.f;
#pragma unroll
        for (int k = 0; k < DIM; ++k) acc += W2[j * DIM + k] * linW[k];
        u[j] = acc;
        float p = b2[j] * linW[j];
#pragma unroll
        for (int off = 32; off; off >>= 1) p += __shfl_down(p, off);
        if (j == 0) cc[0] = p + linb[0];
    }
}

// xd[v] = { dinv[v], bits(x[v]) } — packed so edge1 needs ONE 8B gather
__global__ void k_prep(const int* __restrict__ deg, const int* __restrict__ x,
                       float2* __restrict__ xd, int N) {
    int v = blockIdx.x * blockDim.x + threadIdx.x;
    if (v >= N) return;
    float dv = rsqrtf((float)(deg[v] + 1));
    xd[v] = make_float2(dv, __int_as_float(x[v]));
}

// cnt[dst][x[src]] += dinv[src]   — 1 gather (8B) + 1 atomic per edge
__global__ void k_edge1(const int* __restrict__ src, const int* __restrict__ dst,
                        const float2* __restrict__ xd, float* __restrict__ cnt, int E) {
    int e = blockIdx.x * blockDim.x + threadIdx.x;
    if (e >= E) return;
    int s = src[e], d = dst[e];
    float2 p = xd[s];
    atomicAdd(&cnt[(size_t)d * N_CLS + __float_as_int(p.y)], p.x);
}

// per node v (one wave each):
//   pre[j] = sum_c cnt[v][c]*T1[c][j] + dinv[v]*T1[x[v]][j]   (self-loop folded in)
//   h[j]   = relu(dinv[v]*pre[j] + b1[j])
//   t[v]   = dinv[v] * sum_j h[j]*u[j]
__global__ void k_node1(const float* __restrict__ cnt, const float2* __restrict__ xd,
                        const float* __restrict__ T1, const float* __restrict__ b1,
                        const float* __restrict__ u, float* __restrict__ t, int N) {
    __shared__ float T1s[N_CLS * DIM];
    __shared__ float us[DIM], b1s[DIM];
    int tid = threadIdx.x;
    for (int i = tid; i < N_CLS * DIM; i += blockDim.x) T1s[i] = T1[i];
    if (tid < DIM) { us[tid] = u[tid]; b1s[tid] = b1[tid]; }
    __syncthreads();
    int wave = tid >> 6, lane = tid & 63;
    int v = blockIdx.x * (blockDim.x >> 6) + wave;
    if (v >= N) return;
    float cl = (lane < N_CLS) ? cnt[(size_t)v * N_CLS + lane] : 0.f;
    float2 p = xd[v];                 // uniform address per wave -> broadcast
    float dv = p.x;
    int   xv = __float_as_int(p.y);
    float acc = dv * T1s[xv * DIM + lane];
#pragma unroll
    for (int c = 0; c < N_CLS; ++c) acc += __shfl(cl, c) * T1s[c * DIM + lane];
    float h = fmaxf(dv * acc + b1s[lane], 0.f);
    float q = h * us[lane];
#pragma unroll
    for (int off = 32; off; off >>= 1) q += __shfl_down(q, off);
    if (lane == 0) t[v] = dv * q;
}

// acc2[dst] += t[src]  — dinv[dst] factored out, applied in k_final
__global__ void k_edge2(const int* __restrict__ src, const int* __restrict__ dst,
                        const float* __restrict__ t, float* __restrict__ acc2, int E) {
    int e = blockIdx.x * blockDim.x + threadIdx.x;
    if (e >= E) return;
    atomicAdd(&acc2[dst[e]], t[src[e]]);
}

// y[v] = dinv[v]*(acc2[v] + t[v]) + cc;  out[batch[v]] += y
__global__ void k_final(const float* __restrict__ acc2, const float2* __restrict__ xd,
                        const float* __restrict__ t, const float* __restrict__ cc,
                        const int* __restrict__ batch, float* __restrict__ out, int N) {
    int v = blockIdx.x * blockDim.x + threadIdx.x;
    if (v >= N) return;
    float dv = xd[v].x;
    float y = dv * (acc2[v] + t[v]) + cc[0];
    atomicAdd(&out[batch[v]], y);
}

extern "C" void kernel_launch(void* const* d_in, const int* in_sizes, int n_in,
                              void* d_out, int out_size, void* d_ws, size_t ws_size,
                              hipStream_t stream) {
    const int*   x     = (const int*)d_in[0];
    const int*   ei    = (const int*)d_in[1];
    const int*   batch = (const int*)d_in[3];
    const float* emb   = (const float*)d_in[4];
    const float* W1    = (const float*)d_in[5];
    const float* b1    = (const float*)d_in[6];
    const float* W2    = (const float*)d_in[7];
    const float* b2    = (const float*)d_in[8];
    const float* linW  = (const float*)d_in[9];
    const float* linb  = (const float*)d_in[10];

    const int N = in_sizes[0];
    const int E = in_sizes[1] / 2;
    const int* srcp = ei;
    const int* dstp = ei + E;
    float* out = (float*)d_out;

    // [deg][acc2][cnt] contiguous -> single zeroing memset
    char* w = (char*)d_ws;
    int*    deg  = (int*)w;     w += (size_t)N * 4;
    float*  acc2 = (float*)w;   w += (size_t)N * 4;
    float*  cnt  = (float*)w;   w += (size_t)N * N_CLS * 4;
    float2* xd   = (float2*)w;  w += (size_t)N * 8;
    float*  T1   = (float*)w;   w += (size_t)N_CLS * DIM * 4;
    float*  u    = (float*)w;   w += DIM * 4;
    float*  cc   = (float*)w;   w += 16;
    float*  t    = (float*)w;   w += (size_t)N * 4;

    hipMemsetAsync(deg, 0, (size_t)(N + N + N * N_CLS) * 4, stream);
    hipMemsetAsync(out, 0, (size_t)out_size * 4, stream);

    k_deg  <<<(E + 255) / 256, 256, 0, stream>>>(dstp, deg, E);
    k_const<<<N_CLS + 1, 64, 0, stream>>>(emb, W1, W2, linW, b2, linb, T1, u, cc);
    k_prep <<<(N + 255) / 256, 256, 0, stream>>>(deg, x, xd, N);
    k_edge1<<<(E + 255) / 256, 256, 0, stream>>>(srcp, dstp, xd, cnt, E);
    k_node1<<<(N + 3) / 4, 256, 0, stream>>>(cnt, xd, T1, b1, u, t, N);
    k_edge2<<<(E + 255) / 256, 256, 0, stream>>>(srcp, dstp, t, acc2, E);
    k_final<<<(N + 255) / 256, 256, 0, stream>>>(acc2, xd, t, cc, batch, out, N);
}

// Round 4
// 174.067 us; speedup vs baseline: 1.7138x; 1.6759x over previous
//
#include <hip/hip_runtime.h>

#define N_CLS 28
#define DIM   64
#define SCAN_TILE 1024   // elements per scan block (256 thr x 4)

// ---- pass 1: deg count + insertion position, ONE atomic pass ----
__global__ void k_pos(const int* __restrict__ dst, int* __restrict__ deg,
                      int* __restrict__ pos, int E) {
    int e = blockIdx.x * blockDim.x + threadIdx.x;
    if (e < E) pos[e] = atomicAdd(&deg[dst[e]], 1);
}

// ---- constants: T1 = emb@W1 (blocks 0..27), u = W2@lin_W, cc = b2·lin_W+lin_b ----
__global__ void k_const(const float* __restrict__ emb, const float* __restrict__ W1,
                        const float* __restrict__ W2, const float* __restrict__ linW,
                        const float* __restrict__ b2, const float* __restrict__ linb,
                        float* __restrict__ T1, float* __restrict__ u, float* __restrict__ cc) {
    int j = threadIdx.x;
    int r = blockIdx.x;
    if (r < N_CLS) {
        float acc = 0.f;
#pragma unroll
        for (int k = 0; k < DIM; ++k) acc += emb[r * DIM + k] * W1[k * DIM + j];
        T1[r * DIM + j] = acc;
    } else {
        float acc = 0.f;
#pragma unroll
        for (int k = 0; k < DIM; ++k) acc += W2[j * DIM + k] * linW[k];
        u[j] = acc;
        float p = b2[j] * linW[j];
#pragma unroll
        for (int off = 32; off; off >>= 1) p += __shfl_down(p, off);
        if (j == 0) cc[0] = p + linb[0];
    }
}

// ---- scan step A: per-block sums of deg ----
__global__ void k_bsum(const int* __restrict__ deg, int* __restrict__ bsum, int N) {
    int t = threadIdx.x;
    int v0 = blockIdx.x * SCAN_TILE + t * 4;
    int s = 0;
#pragma unroll
    for (int k = 0; k < 4; ++k) { int v = v0 + k; if (v < N) s += deg[v]; }
#pragma unroll
    for (int off = 32; off; off >>= 1) s += __shfl_down(s, off);
    __shared__ int ws[4];
    if ((t & 63) == 0) ws[t >> 6] = s;
    __syncthreads();
    if (t == 0) bsum[blockIdx.x] = ws[0] + ws[1] + ws[2] + ws[3];
}

// ---- scan step B: exclusive scan of block sums (tiny, 1 thread) ----
__global__ void k_bscan(int* __restrict__ bsum, int nb) {
    int run = 0;
    for (int i = 0; i < nb; ++i) { int t = bsum[i]; bsum[i] = run; run += t; }
}

// ---- scan step C: rowptr = exclusive scan; also pack xd = {dinv, bits(x)} ----
__global__ void k_scanfin(const int* __restrict__ deg, const int* __restrict__ x,
                          const int* __restrict__ bsum, int* __restrict__ rowptr,
                          float2* __restrict__ xd, int N) {
    int t = threadIdx.x;
    int v0 = blockIdx.x * SCAN_TILE + t * 4;
    int d[4]; int s = 0;
#pragma unroll
    for (int k = 0; k < 4; ++k) { int v = v0 + k; d[k] = (v < N) ? deg[v] : 0; s += d[k]; }
    int lane = t & 63, wave = t >> 6;
    int incl = s;
#pragma unroll
    for (int off = 1; off < 64; off <<= 1) {
        int n = __shfl_up(incl, off);
        if (lane >= off) incl += n;
    }
    __shared__ int wtot[4];
    if (lane == 63) wtot[wave] = incl;
    __syncthreads();
    int woff = 0;
    for (int w = 0; w < wave; ++w) woff += wtot[w];
    int run = woff + incl - s + bsum[blockIdx.x];
#pragma unroll
    for (int k = 0; k < 4; ++k) {
        int v = v0 + k;
        if (v < N) {
            rowptr[v] = run;
            xd[v] = make_float2(rsqrtf((float)(d[k] + 1)), __int_as_float(x[v]));
            run += d[k];
        }
    }
}

// ---- scatter edges into CSR: plain writes, no atomics ----
__global__ void k_scatter(const int* __restrict__ src, const int* __restrict__ dst,
                          const int* __restrict__ pos, const int* __restrict__ rowptr,
                          int* __restrict__ csr, int E) {
    int e = blockIdx.x * blockDim.x + threadIdx.x;
    if (e >= E) return;
    int d = dst[e];
    csr[rowptr[d] + pos[e]] = src[e];
}

// ---- layer 1 (pull): wave per node. acc[j] = dinv*T1[x[v]] + sum_in dinv[s]*T1[x[s]]
//      h = relu(dv*acc + b1); t[v] = dv * (h·u) ----
__global__ void __launch_bounds__(1024)
k_gather1(const int* __restrict__ csr, const int* __restrict__ rowptr,
          const int* __restrict__ deg, const float2* __restrict__ xd,
          const float* __restrict__ T1, const float* __restrict__ b1,
          const float* __restrict__ u, float* __restrict__ t, int N) {
    __shared__ float T1s[N_CLS * DIM];
    __shared__ float us[DIM], b1s[DIM];
    __shared__ float2 ebuf[16][64];
    int tid = threadIdx.x;
    for (int i = tid; i < N_CLS * DIM; i += 1024) T1s[i] = T1[i];
    if (tid < DIM) { us[tid] = u[tid]; b1s[tid] = b1[tid]; }
    __syncthreads();
    int wave = tid >> 6, lane = tid & 63;
    int v = blockIdx.x * 16 + wave;
    if (v >= N) return;
    int rp = rowptr[v], d = deg[v];
    float2 pv = xd[v];
    float dv = pv.x;
    int   xv = __float_as_int(pv.y);
    float acc = dv * T1s[(xv << 6) + lane];   // self-loop
    for (int base = 0; base < d; base += 64) {
        int m = min(64, d - base);
        if (lane < m) {
            int s = csr[rp + base + lane];
            float2 p = xd[s];
            ebuf[wave][lane] = make_float2(p.x, __int_as_float(__float_as_int(p.y) << 6));
        }
        // same-wave LDS RAW: DS pipe is in-order per wave, private region per wave
        for (int c = 0; c < m; ++c) {
            float2 p = ebuf[wave][c];
            acc += p.x * T1s[__float_as_int(p.y) + lane];
        }
    }
    float h = fmaxf(dv * acc + b1s[lane], 0.f);
    float q = h * us[lane];
#pragma unroll
    for (int off = 32; off; off >>= 1) q += __shfl_down(q, off);
    if (lane == 0) t[v] = dv * q;
}

// ---- layer 2 (pull) + readout: thread per node ----
__global__ void k_gather2(const int* __restrict__ csr, const int* __restrict__ rowptr,
                          const int* __restrict__ deg, const float2* __restrict__ xd,
                          const float* __restrict__ t, const float* __restrict__ cc,
                          const int* __restrict__ batch, float* __restrict__ out, int N) {
    int v = blockIdx.x * blockDim.x + threadIdx.x;
    if (v >= N) return;
    int rp = rowptr[v], d = deg[v];
    float sum = t[v];                       // self-loop
    for (int i = 0; i < d; ++i) sum += t[csr[rp + i]];
    float y = xd[v].x * sum + cc[0];
    atomicAdd(&out[batch[v]], y);
}

extern "C" void kernel_launch(void* const* d_in, const int* in_sizes, int n_in,
                              void* d_out, int out_size, void* d_ws, size_t ws_size,
                              hipStream_t stream) {
    const int*   x     = (const int*)d_in[0];
    const int*   ei    = (const int*)d_in[1];
    const int*   batch = (const int*)d_in[3];
    const float* emb   = (const float*)d_in[4];
    const float* W1    = (const float*)d_in[5];
    const float* b1    = (const float*)d_in[6];
    const float* W2    = (const float*)d_in[7];
    const float* b2    = (const float*)d_in[8];
    const float* linW  = (const float*)d_in[9];
    const float* linb  = (const float*)d_in[10];

    const int N = in_sizes[0];
    const int E = in_sizes[1] / 2;
    const int* srcp = ei;
    const int* dstp = ei + E;
    float* out = (float*)d_out;

    const int NB = (N + SCAN_TILE - 1) / SCAN_TILE;

    char* w = (char*)d_ws;
    int*    deg    = (int*)w;    w += (size_t)N * 4;
    int*    pos    = (int*)w;    w += (size_t)E * 4;
    int*    rowptr = (int*)w;    w += (size_t)N * 4 + 64;
    int*    csr    = (int*)w;    w += (size_t)E * 4;
    float2* xd     = (float2*)w; w += (size_t)N * 8;
    float*  t      = (float*)w;  w += (size_t)N * 4;
    float*  T1     = (float*)w;  w += (size_t)N_CLS * DIM * 4;
    float*  u      = (float*)w;  w += DIM * 4;
    float*  cc     = (float*)w;  w += 16;
    int*    bsum   = (int*)w;    w += (size_t)NB * 4 + 64;

    hipMemsetAsync(deg, 0, (size_t)N * 4, stream);
    hipMemsetAsync(out, 0, (size_t)out_size * 4, stream);

    k_pos    <<<(E + 255) / 256, 256, 0, stream>>>(dstp, deg, pos, E);
    k_const  <<<N_CLS + 1, 64, 0, stream>>>(emb, W1, W2, linW, b2, linb, T1, u, cc);
    k_bsum   <<<NB, 256, 0, stream>>>(deg, bsum, N);
    k_bscan  <<<1, 1, 0, stream>>>(bsum, NB);
    k_scanfin<<<NB, 256, 0, stream>>>(deg, x, bsum, rowptr, xd, N);
    k_scatter<<<(E + 255) / 256, 256, 0, stream>>>(srcp, dstp, pos, rowptr, csr, E);
    k_gather1<<<(N + 15) / 16, 1024, 0, stream>>>(csr, rowptr, deg, xd, T1, b1, u, t, N);
    k_gather2<<<(N + 255) / 256, 256, 0, stream>>>(csr, rowptr, deg, xd, t, cc, batch, out, N);
}

// Round 5
// 99.624 us; speedup vs baseline: 2.9945x; 1.7472x over previous
//
#include <hip/hip_runtime.h>

#define N_CLS 28
#define DIM   64
#define VB    512            // nodes per bucket
#define VB_SH 9
#define NBKT_MAX 256
#define IPT   20             // items per thread in k_part
#define PTILE (IPT * 256)    // 5120 edges per partition block

// ---- count edges per bucket (block-local LDS hist, tiny global flush) ----
__global__ void k_bcnt(const int* __restrict__ dst, int* __restrict__ bcnt,
                       int E, int nbkt) {
    __shared__ int h[NBKT_MAX];
    int tid = threadIdx.x;
    for (int i = tid; i < nbkt; i += 256) h[i] = 0;
    __syncthreads();
    for (int i = blockIdx.x * 256 + tid; i < E; i += gridDim.x * 256)
        atomicAdd(&h[dst[i] >> VB_SH], 1);
    __syncthreads();
    for (int i = tid; i < nbkt; i += 256) {
        int v = h[i];
        if (v) atomicAdd(&bcnt[i], v);
    }
}

// ---- exclusive scan of bucket counts -> base, cursor ----
__global__ void k_bscan(const int* __restrict__ bcnt, int* __restrict__ base,
                        int* __restrict__ cursor, int nbkt) {
    __shared__ int s[NBKT_MAX];
    int tid = threadIdx.x;
    int v = (tid < nbkt) ? bcnt[tid] : 0;
    s[tid] = v;
    __syncthreads();
    for (int off = 1; off < NBKT_MAX; off <<= 1) {
        int a = (tid >= off) ? s[tid - off] : 0;
        __syncthreads();
        s[tid] += a;
        __syncthreads();
    }
    int incl = s[tid];
    if (tid < nbkt) { base[tid] = incl - v; cursor[tid] = incl - v; }
    if (tid == nbkt - 1) base[nbkt] = incl;
}

// ---- partition edges into buckets: pack src(17b) | d9(9b)<<17 ----
__global__ void __launch_bounds__(256)
k_part(const int* __restrict__ src, const int* __restrict__ dst,
       int* __restrict__ cursor, int* __restrict__ ebkt, int E, int nbkt) {
    __shared__ int h[NBKT_MAX];
    __shared__ int gb[NBKT_MAX];
    int tid = threadIdx.x;
    int start = blockIdx.x * PTILE;
    int end = min(E, start + PTILE);
    for (int i = tid; i < nbkt; i += 256) h[i] = 0;
    __syncthreads();
    int pk[IPT], ar[IPT];
#pragma unroll
    for (int k = 0; k < IPT; ++k) {
        int idx = start + k * 256 + tid;
        ar[k] = -1;
        if (idx < end) {
            int s = src[idx], d = dst[idx];
            int bkt = d >> VB_SH;
            int r = atomicAdd(&h[bkt], 1);     // rank within (block, bucket)
            pk[k] = s | ((d & (VB - 1)) << 17);
            ar[k] = bkt | (r << 8);
        }
    }
    __syncthreads();
    for (int i = tid; i < nbkt; i += 256) {
        int c = h[i];
        gb[i] = c ? atomicAdd(&cursor[i], c) : 0; // one atomic per (block,bucket)
    }
    __syncthreads();
#pragma unroll
    for (int k = 0; k < IPT; ++k) {
        if (ar[k] >= 0) ebkt[gb[ar[k] & 255] + (ar[k] >> 8)] = pk[k];
    }
}

// ---- per-bucket degree count in LDS -> xd = {dinv, bits(x)} ----
__global__ void __launch_bounds__(512)
k_deg(const int* __restrict__ ebkt, const int* __restrict__ base,
      const int* __restrict__ x, float2* __restrict__ xd, int N) {
    __shared__ int dg[VB];
    int tid = threadIdx.x, b = blockIdx.x;
    dg[tid] = 0;
    __syncthreads();
    int e0 = base[b], e1 = base[b + 1];
    for (int i = e0 + tid; i < e1; i += 512)
        atomicAdd(&dg[ebkt[i] >> 17], 1);
    __syncthreads();
    int v = b * VB + tid;
    if (v < N)
        xd[v] = make_float2(rsqrtf((float)(dg[tid] + 1)), __int_as_float(x[v]));
}

// ---- constants: T1 = emb@W1 (blocks 0..27); u = W2@lin_W, cc = b2·lin_W+lin_b ----
__global__ void k_const(const float* __restrict__ emb, const float* __restrict__ W1,
                        const float* __restrict__ W2, const float* __restrict__ linW,
                        const float* __restrict__ b2, const float* __restrict__ linb,
                        float* __restrict__ T1, float* __restrict__ u, float* __restrict__ cc) {
    int j = threadIdx.x;
    int r = blockIdx.x;
    if (r < N_CLS) {
        float acc = 0.f;
#pragma unroll
        for (int k = 0; k < DIM; ++k) acc += emb[r * DIM + k] * W1[k * DIM + j];
        T1[r * DIM + j] = acc;
    } else {
        float acc = 0.f;
#pragma unroll
        for (int k = 0; k < DIM; ++k) acc += W2[j * DIM + k] * linW[k];
        u[j] = acc;
        float p = b2[j] * linW[j];
#pragma unroll
        for (int off = 32; off; off >>= 1) p += __shfl_down(p, off);
        if (j == 0) cc[0] = p + linb[0];
    }
}

// ---- layer 1: per-bucket 512x28 weighted class histogram in LDS, then h1 -> t ----
__global__ void __launch_bounds__(512)
k_l1(const int* __restrict__ ebkt, const int* __restrict__ base,
     const float2* __restrict__ xd, const float* __restrict__ T1,
     const float* __restrict__ b1, const float* __restrict__ u,
     float* __restrict__ t, int N) {
    __shared__ __align__(16) float cnt[VB * N_CLS];   // 57344 B
    __shared__ float T1s[N_CLS * DIM];                // 7168 B
    __shared__ float b1s[DIM], us[DIM];
    int tid = threadIdx.x, b = blockIdx.x;
    for (int i = tid; i < VB * N_CLS; i += 512) cnt[i] = 0.f;
    for (int i = tid; i < N_CLS * DIM; i += 512) T1s[i] = T1[i];
    if (tid < DIM) { b1s[tid] = b1[tid]; us[tid] = u[tid]; }
    __syncthreads();
    int e0 = base[b], e1 = base[b + 1];
    for (int i = e0 + tid; i < e1; i += 512) {
        int p = ebkt[i];
        float2 xs = xd[p & 0x1FFFF];                  // {dinv_s, bits(x_s)} 8B gather
        atomicAdd(&cnt[(p >> 17) * N_CLS + __float_as_int(xs.y)], xs.x);
    }
    __syncthreads();
    int wave = tid >> 6, lane = tid & 63;
    float tc[N_CLS];
#pragma unroll
    for (int c = 0; c < N_CLS; ++c) tc[c] = T1s[c * DIM + lane]; // T1 column in regs
    int v0 = b * VB;
    for (int it = 0; it < VB / 8; ++it) {
        int lv = wave * (VB / 8) + it;
        int v = v0 + lv;
        if (v >= N) break;
        float2 pv = xd[v];
        float dv = pv.x;
        int xv = __float_as_int(pv.y);
        const float4* row = (const float4*)&cnt[lv * N_CLS]; // uniform-addr b128 reads
        float acc = dv * T1s[xv * DIM + lane];               // self-loop
#pragma unroll
        for (int q4 = 0; q4 < 7; ++q4) {
            float4 r = row[q4];
            acc += r.x * tc[q4 * 4 + 0] + r.y * tc[q4 * 4 + 1]
                 + r.z * tc[q4 * 4 + 2] + r.w * tc[q4 * 4 + 3];
        }
        float hh = fmaxf(dv * acc + b1s[lane], 0.f);
        float q = hh * us[lane];
#pragma unroll
        for (int off = 32; off; off >>= 1) q += __shfl_down(q, off);
        if (lane == 0) t[v] = dv * q;
    }
}

// ---- layer 2 + readout: per-bucket LDS accumulate of t[src], LDS graph bins ----
__global__ void __launch_bounds__(512)
k_l2(const int* __restrict__ ebkt, const int* __restrict__ base,
     const float2* __restrict__ xd, const float* __restrict__ t,
     const float* __restrict__ cc, const int* __restrict__ batch,
     float* __restrict__ out, int N) {
    __shared__ float acc[VB];
    __shared__ float og[256];
    __shared__ int g0s;
    int tid = threadIdx.x, b = blockIdx.x;
    acc[tid] = 0.f;
    if (tid < 256) og[tid] = 0.f;
    if (tid == 0) g0s = batch[b * VB];
    __syncthreads();
    int e0 = base[b], e1 = base[b + 1];
    for (int i = e0 + tid; i < e1; i += 512) {
        int p = ebkt[i];
        atomicAdd(&acc[p >> 17], t[p & 0x1FFFF]);
    }
    __syncthreads();
    int v = b * VB + tid;
    if (v < N) {
        float y = xd[v].x * (acc[tid] + t[v]) + cc[0];
        int g = batch[v];
        int off = g - g0s;                 // batch sorted -> off >= 0, small
        if (off < 256) atomicAdd(&og[off], y);
        else atomicAdd(&out[g], y);
    }
    __syncthreads();
    if (tid < 256) {
        float val = og[tid];
        if (val != 0.f) atomicAdd(&out[g0s + tid], val);
    }
}

extern "C" void kernel_launch(void* const* d_in, const int* in_sizes, int n_in,
                              void* d_out, int out_size, void* d_ws, size_t ws_size,
                              hipStream_t stream) {
    const int*   x     = (const int*)d_in[0];
    const int*   ei    = (const int*)d_in[1];
    const int*   batch = (const int*)d_in[3];
    const float* emb   = (const float*)d_in[4];
    const float* W1    = (const float*)d_in[5];
    const float* b1    = (const float*)d_in[6];
    const float* W2    = (const float*)d_in[7];
    const float* b2    = (const float*)d_in[8];
    const float* linW  = (const float*)d_in[9];
    const float* linb  = (const float*)d_in[10];

    const int N = in_sizes[0];
    const int E = in_sizes[1] / 2;
    const int* srcp = ei;
    const int* dstp = ei + E;
    float* out = (float*)d_out;

    const int nbkt = (N + VB - 1) / VB;   // 196 for N=100000

    char* w = (char*)d_ws;
    float2* xd     = (float2*)w; w += (size_t)N * 8;
    float*  t      = (float*)w;  w += (size_t)N * 4;
    int*    ebkt   = (int*)w;    w += ((size_t)E * 4 + 15) & ~15ULL;
    int*    bcnt   = (int*)w;    w += (NBKT_MAX + 4) * 4;
    int*    base   = (int*)w;    w += (NBKT_MAX + 4) * 4;
    int*    cursor = (int*)w;    w += (NBKT_MAX + 4) * 4;
    float*  T1     = (float*)w;  w += (size_t)N_CLS * DIM * 4;
    float*  u      = (float*)w;  w += DIM * 4;
    float*  cc     = (float*)w;  w += 16;

    hipMemsetAsync(bcnt, 0, NBKT_MAX * 4, stream);
    hipMemsetAsync(out, 0, (size_t)out_size * 4, stream);

    k_bcnt <<<256, 256, 0, stream>>>(dstp, bcnt, E, nbkt);
    k_const<<<N_CLS + 1, 64, 0, stream>>>(emb, W1, W2, linW, b2, linb, T1, u, cc);
    k_bscan<<<1, NBKT_MAX, 0, stream>>>(bcnt, base, cursor, nbkt);
    k_part <<<(E + PTILE - 1) / PTILE, 256, 0, stream>>>(srcp, dstp, cursor, ebkt, E, nbkt);
    k_deg  <<<nbkt, 512, 0, stream>>>(ebkt, base, x, xd, N);
    k_l1   <<<nbkt, 512, 0, stream>>>(ebkt, base, xd, T1, b1, u, t, N);
    k_l2   <<<nbkt, 512, 0, stream>>>(ebkt, base, xd, t, cc, batch, out, N);
}